// Round 4
// baseline (1268.197 us; speedup 1.0000x reference)
//
#include <hip/hip_runtime.h>
#include <hip/hip_cooperative_groups.h>
#include <stdint.h>

namespace cg = cooperative_groups;

#define N_PIX 401408
#define NCHUNK 25088   // N_PIX/16
#define HWIMG 12544    // 112*112
#define LN_EPS 1e-5f
#define MAXG 1024

// ---------------- workspace layout (~3.5 MB) ----------------
struct Ws {
  double   partRa[MAXG][8];   // stage-A R0 partials
  double   partRb[MAXG][8];   // sink2 partials
  double   partRc[MAXG][8];   // sink3 partials
  unsigned partC[MAXG][4];    // class-count partials
  float    protoN[8][256];    // l2-normalized prototypes
  float    fAccP[8][2048];    // 8 spread copies of f accumulator (atomics)
  unsigned nmkP[8][8];        // 8 spread copies of per-bucket correct counts
  float2   E2[N_PIX];         // exp(sim/eps) for label class, (m=0, m=1)
};

// ---------------- reductions ----------------
__device__ __forceinline__ float wredf(float v) {
#pragma unroll
  for (int o = 32; o > 0; o >>= 1) v += __shfl_xor(v, o, 64);
  return v;
}
__device__ __forceinline__ float wred16(float v) {
  v += __shfl_xor(v, 1, 64);
  v += __shfl_xor(v, 2, 64);
  v += __shfl_xor(v, 4, 64);
  v += __shfl_xor(v, 8, 64);
  return v;
}
__device__ __forceinline__ double wredd(double v) {
#pragma unroll
  for (int o = 32; o > 0; o >>= 1) v += __shfl_xor(v, o, 64);
  return v;
}

// redundant per-block reduce of [G][8] doubles -> Rf[8] floats (LDS)
__device__ __forceinline__ void red8(const double (*part)[8], int G, int tid,
                                     double* sRed, float* Rf) {
  int j = tid & 7;
  double acc = 0.0;
  for (int i = tid >> 3; i < G; i += 32) acc += part[i][j];
  sRed[tid] = acc;
  __syncthreads();
  if (tid < 8) {
    double t = 0.0;
#pragma unroll
    for (int r2 = 0; r2 < 32; r2++) t += sRed[tid + r2 * 8];
    Rf[tid] = (float)t;
  }
  __syncthreads();
}

// ---------------- the one kernel ----------------
__global__ __launch_bounds__(256, 4) void k_all(
    const float* __restrict__ X, const int* __restrict__ label,
    const float* __restrict__ protos,
    const float* __restrict__ fng, const float* __restrict__ fnb,
    const float* __restrict__ mng, const float* __restrict__ mnb,
    Ws* __restrict__ ws,
    float* __restrict__ out_nearest, float* __restrict__ out_logits,
    float* __restrict__ out_target, float* __restrict__ out_protos) {
  cg::grid_group grid = cg::this_grid();

  __shared__ float bigS[8192];         // A: prS in [0..2047]; G: 4x2048 f acc
  __shared__ double sRed[256];
  __shared__ float Rf[8], su1[8], su2[8], su3[8], sBn[4];
  __shared__ unsigned short sList[800];
  __shared__ unsigned sCorr;
  __shared__ double sRd[4][8];
  __shared__ unsigned sC4[4][4];
  __shared__ unsigned ldc[4][8];

  const int tid = threadIdx.x;
  const int bid = blockIdx.x;
  const int G = gridDim.x;
  const int wave = tid >> 6, lane = tid & 63;
  if (tid == 0) sCorr = 0u;

  // zero spread accumulators (ordered before use by grid syncs)
  if (bid < 8) {
    for (int i = tid; i < 2048; i += 256) ws->fAccP[bid][i] = 0.f;
    if (tid < 8) ws->nmkP[bid][tid] = 0u;
  }

  // ---- stage A prologue: normalize protos into swizzled LDS ----
  float* prS = bigS;
#pragma unroll
  for (int t = 0; t < 2; t++) {
    int r = wave + t * 4;
    const float4 p = *(const float4*)(protos + r * 256 + lane * 4);
    float ss = p.x * p.x + p.y * p.y + p.z * p.z + p.w * p.w;
    ss = wredf(ss);
    float inv = 1.0f / fmaxf(sqrtf(ss), 1e-12f);
    float4 o; o.x = p.x * inv; o.y = p.y * inv; o.z = p.z * inv; o.w = p.w * inv;
    *(float4*)(&prS[lane * 32 + 4 * (r ^ (lane & 7))]) = o;
    if (bid == 0) *(float4*)(&ws->protoN[r][lane * 4]) = o;
  }
  __syncthreads();

  const int grp = lane >> 4, s = lane & 15;
  const float* gb = fng + s * 4;
  const float* bb = fnb + s * 4;
  const float4 g0 = *(const float4*)(gb);
  const float4 g1 = *(const float4*)(gb + 64);
  const float4 g2 = *(const float4*)(gb + 128);
  const float4 g3 = *(const float4*)(gb + 192);
  const float4 b0 = *(const float4*)(bb);
  const float4 b1 = *(const float4*)(bb + 64);
  const float4 b2 = *(const float4*)(bb + 128);
  const float4 b3 = *(const float4*)(bb + 192);
  const int k = (s >> 1) & 3;
  const float mngk = mng[k], mnbk = mnb[k];

  double rAcc = 0.0;
  unsigned cAcc = 0u;

  // ---- stage A: per-pixel main, grid-stride over 16-pixel chunks ----
  int it = 0;
  for (int ch = bid; ch < NCHUNK; ch += G, ++it) {
    int n = ch * 16 + wave * 4 + grp;

    const float* xb = X + (size_t)n * 256 + s * 4;
    const float4 x0 = *(const float4*)(xb);
    const float4 x1 = *(const float4*)(xb + 64);
    const float4 x2 = *(const float4*)(xb + 128);
    const float4 x3 = *(const float4*)(xb + 192);
    int lab = label[n];

    float sm = (x0.x + x0.y + x0.z + x0.w) + (x1.x + x1.y + x1.z + x1.w) +
               (x2.x + x2.y + x2.z + x2.w) + (x3.x + x3.y + x3.z + x3.w);
    float q = x0.x * x0.x + x0.y * x0.y + x0.z * x0.z + x0.w * x0.w +
              x1.x * x1.x + x1.y * x1.y + x1.z * x1.z + x1.w * x1.w +
              x2.x * x2.x + x2.y * x2.y + x2.z * x2.z + x2.w * x2.w +
              x3.x * x3.x + x3.y * x3.y + x3.z * x3.z + x3.w * x3.w;
    sm = wred16(sm); q = wred16(q);
    float mu = sm * (1.0f / 256.0f);
    float var = q * (1.0f / 256.0f) - mu * mu;
    float rstd = rsqrtf(var + LN_EPS);

    float4 y0, y1, y2, y3;
    y0.x = (x0.x - mu) * rstd * g0.x + b0.x; y0.y = (x0.y - mu) * rstd * g0.y + b0.y;
    y0.z = (x0.z - mu) * rstd * g0.z + b0.z; y0.w = (x0.w - mu) * rstd * g0.w + b0.w;
    y1.x = (x1.x - mu) * rstd * g1.x + b1.x; y1.y = (x1.y - mu) * rstd * g1.y + b1.y;
    y1.z = (x1.z - mu) * rstd * g1.z + b1.z; y1.w = (x1.w - mu) * rstd * g1.w + b1.w;
    y2.x = (x2.x - mu) * rstd * g2.x + b2.x; y2.y = (x2.y - mu) * rstd * g2.y + b2.y;
    y2.z = (x2.z - mu) * rstd * g2.z + b2.z; y2.w = (x2.w - mu) * rstd * g2.w + b2.w;
    y3.x = (x3.x - mu) * rstd * g3.x + b3.x; y3.y = (x3.y - mu) * rstd * g3.y + b3.y;
    y3.z = (x3.z - mu) * rstd * g3.z + b3.z; y3.w = (x3.w - mu) * rstd * g3.w + b3.w;

    float qq = y0.x * y0.x + y0.y * y0.y + y0.z * y0.z + y0.w * y0.w +
               y1.x * y1.x + y1.y * y1.y + y1.z * y1.z + y1.w * y1.w +
               y2.x * y2.x + y2.y * y2.y + y2.z * y2.z + y2.w * y2.w +
               y3.x * y3.x + y3.y * y3.y + y3.z * y3.z + y3.w * y3.w;
    qq = wred16(qq);

    float dot[8];
#pragma unroll
    for (int j = 0; j < 8; j++) {
      int jx = 4 * (j ^ (s & 7));
      const float4 pa = *(const float4*)(&prS[s * 32 + jx]);
      const float4 pb = *(const float4*)(&prS[(16 + s) * 32 + jx]);
      const float4 pc = *(const float4*)(&prS[(32 + s) * 32 + jx]);
      const float4 pd = *(const float4*)(&prS[(48 + s) * 32 + jx]);
      dot[j] = y0.x * pa.x + y0.y * pa.y + y0.z * pa.z + y0.w * pa.w +
               y1.x * pb.x + y1.y * pb.y + y1.z * pb.z + y1.w * pb.w +
               y2.x * pc.x + y2.y * pc.y + y2.z * pc.z + y2.w * pc.w +
               y3.x * pd.x + y3.y * pd.y + y3.z * pd.z + y3.w * pd.w;
    }
    int b0s = s & 1, b1s = (s >> 1) & 1, b2s = (s >> 2) & 1;
    float e0 = b0s ? dot[1] : dot[0], o0 = b0s ? dot[0] : dot[1];
    float e1 = b0s ? dot[3] : dot[2], o1 = b0s ? dot[2] : dot[3];
    float e2 = b0s ? dot[5] : dot[4], o2 = b0s ? dot[4] : dot[5];
    float e3 = b0s ? dot[7] : dot[6], o3 = b0s ? dot[6] : dot[7];
    e0 += __shfl_xor(o0, 1, 64);
    e1 += __shfl_xor(o1, 1, 64);
    e2 += __shfl_xor(o2, 1, 64);
    e3 += __shfl_xor(o3, 1, 64);
    float f0 = b1s ? e1 : e0, p0 = b1s ? e0 : e1;
    float f1 = b1s ? e3 : e2, p1 = b1s ? e2 : e3;
    f0 += __shfl_xor(p0, 2, 64);
    f1 += __shfl_xor(p1, 2, 64);
    float h = b2s ? f1 : f0, ph = b2s ? f0 : f1;
    h += __shfl_xor(ph, 4, 64);
    float v = h + __shfl_xor(h, 8, 64);

    float invq = 1.0f / fmaxf(sqrtf(qq), 1e-12f);
    float d = v * invq;

    if (s < 8) out_logits[(size_t)n * 8 + ((s & 1) << 2) + (s >> 1)] = d;

    float nm = fmaxf(d, __shfl_xor(d, 1, 64));
    float tA = __shfl_xor(nm, 2, 64);
    float s2 = nm + tA, q2 = nm * nm + tA * tA;
    float s4 = s2 + __shfl_xor(s2, 4, 64);
    float q4 = q2 + __shfl_xor(q2, 4, 64);
    float m4 = 0.25f * s4;
    float v4 = 0.25f * q4 - m4 * m4;
    float rs4 = rsqrtf(v4 + LN_EPS);
    float lnv = (nm - m4) * rs4 * mngk + mnbk;

    int bimg = n / HWIMG;
    int p = n - bimg * HWIMG;
    if (s < 8 && (s & 1) == 0)
      out_nearest[((size_t)bimg * 4 + k) * HWIMG + p] = lnv;

    float av = lnv; int ak = k;
#pragma unroll
    for (int o = 2; o <= 4; o <<= 1) {
      float ov = __shfl_xor(av, o, 64);
      int ok = __shfl_xor(ak, o, 64);
      bool take = (ov > av) || (ov == av && ok < ak);
      av = take ? ov : av;
      ak = take ? ok : ak;
    }

    float Ev = expf(d / 0.05f);
    bool isLab = (s < 8) && ((s >> 1) == lab);
    if (isLab) ((float*)(ws->E2 + n))[s & 1] = Ev;
    float val = isLab ? Ev : 0.f;
    val += __shfl_xor(val, 16, 64);
    val += __shfl_xor(val, 32, 64);
    rAcc += (double)val;
    unsigned cu = ((s < 8) && !(s & 1) && ((s >> 1) == lab)) ? 1u : 0u;
    cu += (unsigned)__shfl_xor((int)cu, 16, 64);
    cu += (unsigned)__shfl_xor((int)cu, 32, 64);
    cAcc += cu;

    if (s == 0 && lab == ak) {
      unsigned pos = atomicAdd(&sCorr, 1u);
      sList[pos] = (unsigned short)(it * 16 + wave * 4 + grp);
    }
  }

  // stage A epilogue: per-block partials (plain stores)
  if (lane < 8) sRd[wave][lane] = rAcc;
  if (lane < 8 && !(lane & 1)) sC4[wave][lane >> 1] = cAcc;
  __syncthreads();
  if (tid < 8)
    ws->partRa[bid][tid] = sRd[0][tid] + sRd[1][tid] + sRd[2][tid] + sRd[3][tid];
  if (tid < 4)
    ws->partC[bid][tid] = sC4[0][tid] + sC4[1][tid] + sC4[2][tid] + sC4[3][tid];

  grid.sync();   // ---- s1: R0 / cnt4 / E2 complete ----

  // ---- stage B: redundant reduce -> R0, Bn, su1 ----
  red8(ws->partRa, G, tid, sRed, Rf);
  if (tid < 8) {
    int c = tid >> 1;
    float S = Rf[c * 2] + Rf[c * 2 + 1];
    float uu0 = 1.0f / fmaxf(S, 1e-30f);
    su1[tid] = uu0 / (fmaxf(uu0 * Rf[tid], 1e-30f) * 2.0f);
  }
  {
    unsigned* sRu = (unsigned*)sRed;
    int c4 = tid & 3;
    unsigned ua = 0;
    for (int i = tid >> 2; i < G; i += 64) ua += ws->partC[i][c4];
    __syncthreads();
    sRu[tid] = ua;
    __syncthreads();
    if (tid < 4) {
      unsigned t = 0;
#pragma unroll
      for (int r2 = 0; r2 < 64; r2++) t += sRu[tid + r2 * 4];
      sBn[tid] = fmaxf((float)t, 1.0f);
    }
    __syncthreads();
  }

  // ---- stage C: sink iter 2 partials ----
  {
    double a0 = 0, a1 = 0, a2 = 0, a3 = 0, a4 = 0, a5 = 0, a6 = 0, a7 = 0;
    int T = G * 256;
    for (int n = bid * 256 + tid; n < N_PIX; n += T) {
      int c = label[n];
      float2 e = ws->E2[n];
      float S1 = su1[c * 2] * e.x + su1[c * 2 + 1] * e.y;
      float v1 = 1.0f / (fmaxf(S1, 1e-30f) * sBn[c]);
      double t0 = (double)(v1 * e.x), t1 = (double)(v1 * e.y);
      if (c == 0) { a0 += t0; a1 += t1; }
      else if (c == 1) { a2 += t0; a3 += t1; }
      else if (c == 2) { a4 += t0; a5 += t1; }
      else { a6 += t0; a7 += t1; }
    }
    a0 = wredd(a0); a1 = wredd(a1); a2 = wredd(a2); a3 = wredd(a3);
    a4 = wredd(a4); a5 = wredd(a5); a6 = wredd(a6); a7 = wredd(a7);
    if (lane == 0) {
      sRd[wave][0] = a0; sRd[wave][1] = a1; sRd[wave][2] = a2; sRd[wave][3] = a3;
      sRd[wave][4] = a4; sRd[wave][5] = a5; sRd[wave][6] = a6; sRd[wave][7] = a7;
    }
    __syncthreads();
    if (tid < 8)
      ws->partRb[bid][tid] = sRd[0][tid] + sRd[1][tid] + sRd[2][tid] + sRd[3][tid];
  }

  grid.sync();   // ---- s2: R1 complete ----

  // ---- stage D: reduce -> su2 ----
  red8(ws->partRb, G, tid, sRed, Rf);
  if (tid < 8)
    su2[tid] = su1[tid] / (fmaxf(su1[tid] * Rf[tid], 1e-30f) * 2.0f);
  __syncthreads();

  // ---- stage E: sink iter 3 partials ----
  {
    double a0 = 0, a1 = 0, a2 = 0, a3 = 0, a4 = 0, a5 = 0, a6 = 0, a7 = 0;
    int T = G * 256;
    for (int n = bid * 256 + tid; n < N_PIX; n += T) {
      int c = label[n];
      float2 e = ws->E2[n];
      float S1 = su1[c * 2] * e.x + su1[c * 2 + 1] * e.y;
      float v1 = 1.0f / (fmaxf(S1, 1e-30f) * sBn[c]);
      float S2 = su2[c * 2] * e.x + su2[c * 2 + 1] * e.y;
      float v = v1 / (fmaxf(v1 * S2, 1e-30f) * sBn[c]);
      double t0 = (double)(v * e.x), t1 = (double)(v * e.y);
      if (c == 0) { a0 += t0; a1 += t1; }
      else if (c == 1) { a2 += t0; a3 += t1; }
      else if (c == 2) { a4 += t0; a5 += t1; }
      else { a6 += t0; a7 += t1; }
    }
    a0 = wredd(a0); a1 = wredd(a1); a2 = wredd(a2); a3 = wredd(a3);
    a4 = wredd(a4); a5 = wredd(a5); a6 = wredd(a6); a7 = wredd(a7);
    if (lane == 0) {
      sRd[wave][0] = a0; sRd[wave][1] = a1; sRd[wave][2] = a2; sRd[wave][3] = a3;
      sRd[wave][4] = a4; sRd[wave][5] = a5; sRd[wave][6] = a6; sRd[wave][7] = a7;
    }
    __syncthreads();
    if (tid < 8)
      ws->partRc[bid][tid] = sRd[0][tid] + sRd[1][tid] + sRd[2][tid] + sRd[3][tid];
  }

  grid.sync();   // ---- s3: R2 complete ----

  // ---- stage F: reduce -> su3 ----
  red8(ws->partRc, G, tid, sRed, Rf);
  if (tid < 8)
    su3[tid] = su2[tid] / (fmaxf(su2[tid] * Rf[tid], 1e-30f) * 2.0f);
  __syncthreads();

  // ---- stage G: proto_target (all pixels) + gather over block's LDS list ----
  {
    int T = G * 256;
    for (int n = bid * 256 + tid; n < N_PIX; n += T) {
      int c = label[n];
      float2 e = ws->E2[n];
      int idx = (su3[c * 2 + 1] * e.y > su3[c * 2] * e.x) ? 1 : 0;
      out_target[n] = (float)(idx + 2 * c);
    }

    float* myAcc = &bigS[wave * 2048];
    for (int i = lane; i < 2048; i += 64) myAcc[i] = 0.f;

    const float4 g4 = *(const float4*)(fng + lane * 4);
    const float4 b4 = *(const float4*)(fnb + lane * 4);
    unsigned cl[8] = {0, 0, 0, 0, 0, 0, 0, 0};
    unsigned nc = sCorr;
    for (unsigned base = wave * 4; base < nc; base += 16) {
      int m = (int)min(4u, nc - base);
      int bk[4]; float4 xx[4];
#pragma unroll
      for (int g = 0; g < 4; g++) if (g < m) {
        int lid = sList[base + g];
        int n = (bid + (lid >> 4) * G) * 16 + (lid & 15);
        int c = label[n];
        float2 e = ws->E2[n];
        int idx = (su3[c * 2 + 1] * e.y > su3[c * 2] * e.x) ? 1 : 0;
        bk[g] = c * 2 + idx;
        xx[g] = *(const float4*)(X + (size_t)n * 256 + lane * 4);
      }
      float svr[4], qvr[4];
#pragma unroll
      for (int g = 0; g < 4; g++) if (g < m) {
        float4 x = xx[g];
        float sv = x.x + x.y + x.z + x.w;
        float qv = x.x * x.x + x.y * x.y + x.z * x.z + x.w * x.w;
        svr[g] = wredf(sv); qvr[g] = wredf(qv);
      }
      float4 yy[4]; float qqr[4];
#pragma unroll
      for (int g = 0; g < 4; g++) if (g < m) {
        float mu = svr[g] * (1.0f / 256.0f);
        float var = qvr[g] * (1.0f / 256.0f) - mu * mu;
        float rstd = rsqrtf(var + LN_EPS);
        float4 x = xx[g];
        float4 y;
        y.x = (x.x - mu) * rstd * g4.x + b4.x;
        y.y = (x.y - mu) * rstd * g4.y + b4.y;
        y.z = (x.z - mu) * rstd * g4.z + b4.z;
        y.w = (x.w - mu) * rstd * g4.w + b4.w;
        yy[g] = y;
        qqr[g] = wredf(y.x * y.x + y.y * y.y + y.z * y.z + y.w * y.w);
      }
#pragma unroll
      for (int g = 0; g < 4; g++) if (g < m) {
        float invq = 1.0f / fmaxf(sqrtf(qqr[g]), 1e-12f);
        float4 y = yy[g];
        float* dst = myAcc + bk[g] * 256 + lane * 4;
        dst[0] += y.x * invq; dst[1] += y.y * invq;
        dst[2] += y.z * invq; dst[3] += y.w * invq;
        if (lane == 0) cl[bk[g]]++;
      }
    }
    if (lane == 0) {
#pragma unroll
      for (int j = 0; j < 8; j++) ldc[wave][j] = cl[j];
    }
    __syncthreads();
    float* fg = &ws->fAccP[bid & 7][0];
    for (int i = tid; i < 2048; i += 256) {
      float ssum = bigS[i] + bigS[2048 + i] + bigS[4096 + i] + bigS[6144 + i];
      unsafeAtomicAdd(fg + i, ssum);
    }
    if (tid < 8) {
      unsigned cs = ldc[0][tid] + ldc[1][tid] + ldc[2][tid] + ldc[3][tid];
      if (cs) atomicAdd(&ws->nmkP[bid & 7][tid], cs);
    }
  }

  grid.sync();   // ---- s4: fAcc / nmk complete ----

  // ---- stage H: finalize prototypes (8 blocks, wave 0) ----
  if (bid < 8 && wave == 0) {
    int r = bid;
    float4 f = {0.f, 0.f, 0.f, 0.f};
#pragma unroll
    for (int p = 0; p < 8; p++) {
      const float4 t = *(const float4*)(&ws->fAccP[p][r * 256 + lane * 4]);
      f.x += t.x; f.y += t.y; f.z += t.z; f.w += t.w;
    }
    unsigned nr = 0, nsib = 0;
#pragma unroll
    for (int p = 0; p < 8; p++) { nr += ws->nmkP[p][r]; nsib += ws->nmkP[p][r ^ 1]; }
    float ss = wredf(f.x * f.x + f.y * f.y + f.z * f.z + f.w * f.w);
    float invf = 1.0f / fmaxf(sqrtf(ss), 1e-12f);
    unsigned tot = nr + nsib;
    bool cond = (tot > 0u) && (nr != 0u);
    const float4 p4 = *(const float4*)(&ws->protoN[r][lane * 4]);
    float u0 = cond ? 0.999f * p4.x + 0.001f * (f.x * invf) : p4.x;
    float u1 = cond ? 0.999f * p4.y + 0.001f * (f.y * invf) : p4.y;
    float u2 = cond ? 0.999f * p4.z + 0.001f * (f.z * invf) : p4.z;
    float u3 = cond ? 0.999f * p4.w + 0.001f * (f.w * invf) : p4.w;
    float ss2 = wredf(u0 * u0 + u1 * u1 + u2 * u2 + u3 * u3);
    float invn = 1.0f / fmaxf(sqrtf(ss2), 1e-12f);
    float4 o; o.x = u0 * invn; o.y = u1 * invn; o.z = u2 * invn; o.w = u3 * invn;
    *(float4*)(out_protos + r * 256 + lane * 4) = o;
  }
}

// ---------------- launch ----------------
extern "C" void kernel_launch(void* const* d_in, const int* in_sizes, int n_in,
                              void* d_out, int out_size, void* d_ws, size_t ws_size,
                              hipStream_t stream) {
  const float* X = (const float*)d_in[0];
  const int* label = (const int*)d_in[1];
  const float* protos = (const float*)d_in[2];
  const float* fng = (const float*)d_in[3];
  const float* fnb = (const float*)d_in[4];
  const float* mng = (const float*)d_in[5];
  const float* mnb = (const float*)d_in[6];

  float* out = (float*)d_out;
  float* out_nearest = out;                        // 32*4*12544 = 1605632
  float* out_logits = out + 1605632;               // N*8 = 3211264
  float* out_target = out_logits + 3211264;        // N
  float* out_protos = out_target + N_PIX;          // 2048
  Ws* ws = (Ws*)d_ws;

  int occ = 0;
  hipOccupancyMaxActiveBlocksPerMultiprocessor(&occ, k_all, 256, 0);
  int G = occ * 256;
  if (G < 512) G = 512;
  if (G > MAXG) G = MAXG;

  void* args[] = {(void*)&X, (void*)&label, (void*)&protos,
                  (void*)&fng, (void*)&fnb, (void*)&mng, (void*)&mnb,
                  (void*)&ws, (void*)&out_nearest, (void*)&out_logits,
                  (void*)&out_target, (void*)&out_protos};
  hipLaunchCooperativeKernel((void*)k_all, dim3(G), dim3(256), args, 0, stream);
}

// Round 5
// 884.712 us; speedup vs baseline: 1.4335x; 1.4335x over previous
//
#include <hip/hip_runtime.h>
#include <hip/hip_cooperative_groups.h>
#include <stdint.h>

namespace cg = cooperative_groups;

#define N_PIX 401408
#define HWIMG 12544   // 112*112
#define LN_EPS 1e-5f
#define NBLK 3136     // k_main blocks (128 pixels each)
#define ITERS 8       // pixel-iterations per k_main block (16 pixels each)
#define GREST 512     // k_rest blocks (cooperative; 35KB LDS -> 4 blocks/CU, co-resident)

// ---------------- workspace layout (~4.0 MB) ----------------
struct Ws {
  double   partR[NBLK][8];    // k_main R0 partials (plain stores, no atomics)
  double   partR2[GREST][8];  // sink2 partials
  double   partR3[GREST][8];  // sink3 partials
  unsigned partC[NBLK][4];    // class-count partials
  unsigned partNc[NBLK];      // per-block correct-pixel count
  float    protoN[8][256];    // l2-normalized prototypes
  float    fAccP[8][2048];    // 8 spread copies of f accumulator
  unsigned nmkP[8][8];        // 8 spread copies of per-bucket correct counts
  unsigned char corrTmp[NBLK][128]; // correct-pixel offsets (n = b*128+off)
  float2   E2[N_PIX];         // exp(sim/eps) for label class, (m=0, m=1)
};

// ---------------- reductions ----------------
__device__ __forceinline__ float wredf(float v) {
#pragma unroll
  for (int o = 32; o > 0; o >>= 1) v += __shfl_xor(v, o, 64);
  return v;
}
__device__ __forceinline__ float wred16(float v) {
  v += __shfl_xor(v, 1, 64);
  v += __shfl_xor(v, 2, 64);
  v += __shfl_xor(v, 4, 64);
  v += __shfl_xor(v, 8, 64);
  return v;
}
__device__ __forceinline__ double wredd(double v) {
#pragma unroll
  for (int o = 32; o > 0; o >>= 1) v += __shfl_xor(v, o, 64);
  return v;
}

// ---------------- K1: per-pixel main (round-3 proven version) ----------------
// 16 lanes per pixel, 4 pixels per wave, 16 pixels per block-iteration,
// 8 iterations per block. NO global atomics: per-block partials via stores.
__global__ __launch_bounds__(256) void k_main(
    const float* __restrict__ X, const int* __restrict__ label,
    const float* __restrict__ protos,
    const float* __restrict__ fng, const float* __restrict__ fnb,
    const float* __restrict__ mng, const float* __restrict__ mnb,
    Ws* __restrict__ ws,
    float* __restrict__ out_nearest, float* __restrict__ out_logits) {
  __shared__ float prS[2048];
  __shared__ double sRd[4][8];
  __shared__ unsigned sC4[4][4];
  __shared__ unsigned sCorr;
  __shared__ unsigned char sList[128];
  int tid = threadIdx.x;
  int wave = tid >> 6, lane = tid & 63;
  if (tid == 0) sCorr = 0u;

  // normalize prototypes into swizzled LDS (each wave does rows w, w+4)
#pragma unroll
  for (int t = 0; t < 2; t++) {
    int r = wave + t * 4;
    const float4 p = *(const float4*)(protos + r * 256 + lane * 4);
    float ss = p.x * p.x + p.y * p.y + p.z * p.z + p.w * p.w;
    ss = wredf(ss);
    float inv = 1.0f / fmaxf(sqrtf(ss), 1e-12f);
    float4 o; o.x = p.x * inv; o.y = p.y * inv; o.z = p.z * inv; o.w = p.w * inv;
    *(float4*)(&prS[lane * 32 + 4 * (r ^ (lane & 7))]) = o;
    if (blockIdx.x == 0) *(float4*)(&ws->protoN[r][lane * 4]) = o;
  }
  __syncthreads();

  int grp = lane >> 4, s = lane & 15;

  const float* gb = fng + s * 4;
  const float* bb = fnb + s * 4;
  const float4 g0 = *(const float4*)(gb);
  const float4 g1 = *(const float4*)(gb + 64);
  const float4 g2 = *(const float4*)(gb + 128);
  const float4 g3 = *(const float4*)(gb + 192);
  const float4 b0 = *(const float4*)(bb);
  const float4 b1 = *(const float4*)(bb + 64);
  const float4 b2 = *(const float4*)(bb + 128);
  const float4 b3 = *(const float4*)(bb + 192);
  int k = (s >> 1) & 3;
  float mngk = mng[k], mnbk = mnb[k];

  double rAcc = 0.0;      // lanes 0..7: R0 partial for (c,m)=lane
  unsigned cAcc = 0u;     // lanes 0,2,4,6: class counts

#pragma unroll 1
  for (int it = 0; it < ITERS; ++it) {
    int n = blockIdx.x * (16 * ITERS) + it * 16 + wave * 4 + grp;

    const float* xb = X + (size_t)n * 256 + s * 4;
    const float4 x0 = *(const float4*)(xb);         // dims 4s..4s+3
    const float4 x1 = *(const float4*)(xb + 64);
    const float4 x2 = *(const float4*)(xb + 128);
    const float4 x3 = *(const float4*)(xb + 192);
    int lab = label[n];

    float sm = (x0.x + x0.y + x0.z + x0.w) + (x1.x + x1.y + x1.z + x1.w) +
               (x2.x + x2.y + x2.z + x2.w) + (x3.x + x3.y + x3.z + x3.w);
    float q = x0.x * x0.x + x0.y * x0.y + x0.z * x0.z + x0.w * x0.w +
              x1.x * x1.x + x1.y * x1.y + x1.z * x1.z + x1.w * x1.w +
              x2.x * x2.x + x2.y * x2.y + x2.z * x2.z + x2.w * x2.w +
              x3.x * x3.x + x3.y * x3.y + x3.z * x3.z + x3.w * x3.w;
    sm = wred16(sm); q = wred16(q);
    float mu = sm * (1.0f / 256.0f);
    float var = q * (1.0f / 256.0f) - mu * mu;
    float rstd = rsqrtf(var + LN_EPS);

    float4 y0, y1, y2, y3;
    y0.x = (x0.x - mu) * rstd * g0.x + b0.x; y0.y = (x0.y - mu) * rstd * g0.y + b0.y;
    y0.z = (x0.z - mu) * rstd * g0.z + b0.z; y0.w = (x0.w - mu) * rstd * g0.w + b0.w;
    y1.x = (x1.x - mu) * rstd * g1.x + b1.x; y1.y = (x1.y - mu) * rstd * g1.y + b1.y;
    y1.z = (x1.z - mu) * rstd * g1.z + b1.z; y1.w = (x1.w - mu) * rstd * g1.w + b1.w;
    y2.x = (x2.x - mu) * rstd * g2.x + b2.x; y2.y = (x2.y - mu) * rstd * g2.y + b2.y;
    y2.z = (x2.z - mu) * rstd * g2.z + b2.z; y2.w = (x2.w - mu) * rstd * g2.w + b2.w;
    y3.x = (x3.x - mu) * rstd * g3.x + b3.x; y3.y = (x3.y - mu) * rstd * g3.y + b3.y;
    y3.z = (x3.z - mu) * rstd * g3.z + b3.z; y3.w = (x3.w - mu) * rstd * g3.w + b3.w;

    float qq = y0.x * y0.x + y0.y * y0.y + y0.z * y0.z + y0.w * y0.w +
               y1.x * y1.x + y1.y * y1.y + y1.z * y1.z + y1.w * y1.w +
               y2.x * y2.x + y2.y * y2.y + y2.z * y2.z + y2.w * y2.w +
               y3.x * y3.x + y3.y * y3.y + y3.z * y3.z + y3.w * y3.w;
    qq = wred16(qq);

    float dot[8];
#pragma unroll
    for (int j = 0; j < 8; j++) {
      int jx = 4 * (j ^ (s & 7));
      const float4 pa = *(const float4*)(&prS[s * 32 + jx]);
      const float4 pb = *(const float4*)(&prS[(16 + s) * 32 + jx]);
      const float4 pc = *(const float4*)(&prS[(32 + s) * 32 + jx]);
      const float4 pd = *(const float4*)(&prS[(48 + s) * 32 + jx]);
      dot[j] = y0.x * pa.x + y0.y * pa.y + y0.z * pa.z + y0.w * pa.w +
               y1.x * pb.x + y1.y * pb.y + y1.z * pb.z + y1.w * pb.w +
               y2.x * pc.x + y2.y * pc.y + y2.z * pc.z + y2.w * pc.w +
               y3.x * pd.x + y3.y * pd.y + y3.z * pd.z + y3.w * pd.w;
    }
    // transpose-reduce: 8 shuffles total. Lane s ends with full dot[s&7].
    int b0s = s & 1, b1s = (s >> 1) & 1, b2s = (s >> 2) & 1;
    float e0 = b0s ? dot[1] : dot[0], o0 = b0s ? dot[0] : dot[1];
    float e1 = b0s ? dot[3] : dot[2], o1 = b0s ? dot[2] : dot[3];
    float e2 = b0s ? dot[5] : dot[4], o2 = b0s ? dot[4] : dot[5];
    float e3 = b0s ? dot[7] : dot[6], o3 = b0s ? dot[6] : dot[7];
    e0 += __shfl_xor(o0, 1, 64);
    e1 += __shfl_xor(o1, 1, 64);
    e2 += __shfl_xor(o2, 1, 64);
    e3 += __shfl_xor(o3, 1, 64);
    float f0 = b1s ? e1 : e0, p0 = b1s ? e0 : e1;
    float f1 = b1s ? e3 : e2, p1 = b1s ? e2 : e3;
    f0 += __shfl_xor(p0, 2, 64);
    f1 += __shfl_xor(p1, 2, 64);
    float h = b2s ? f1 : f0, ph = b2s ? f0 : f1;
    h += __shfl_xor(ph, 4, 64);
    float v = h + __shfl_xor(h, 8, 64);

    float invq = 1.0f / fmaxf(sqrtf(qq), 1e-12f);
    float d = v * invq;   // lane s (and s+8) holds dot j = s&7 = (k=s>>1, m=s&1)

    if (s < 8) out_logits[(size_t)n * 8 + ((s & 1) << 2) + (s >> 1)] = d;

    float nm = fmaxf(d, __shfl_xor(d, 1, 64));
    float tA = __shfl_xor(nm, 2, 64);
    float s2 = nm + tA, q2 = nm * nm + tA * tA;
    float s4 = s2 + __shfl_xor(s2, 4, 64);
    float q4 = q2 + __shfl_xor(q2, 4, 64);
    float m4 = 0.25f * s4;
    float v4 = 0.25f * q4 - m4 * m4;
    float rs4 = rsqrtf(v4 + LN_EPS);
    float lnv = (nm - m4) * rs4 * mngk + mnbk;

    int bimg = n / HWIMG;
    int p = n - bimg * HWIMG;
    if (s < 8 && (s & 1) == 0)
      out_nearest[((size_t)bimg * 4 + k) * HWIMG + p] = lnv;

    float av = lnv; int ak = k;
#pragma unroll
    for (int o = 2; o <= 4; o <<= 1) {
      float ov = __shfl_xor(av, o, 64);
      int ok = __shfl_xor(ak, o, 64);
      bool take = (ov > av) || (ov == av && ok < ak);
      av = take ? ov : av;
      ak = take ? ok : ak;
    }

    float Ev = expf(d / 0.05f);
    bool isLab = (s < 8) && ((s >> 1) == lab);
    if (isLab) ((float*)(ws->E2 + n))[s & 1] = Ev;
    float val = isLab ? Ev : 0.f;
    val += __shfl_xor(val, 16, 64);
    val += __shfl_xor(val, 32, 64);
    rAcc += (double)val;
    unsigned cu = ((s < 8) && !(s & 1) && ((s >> 1) == lab)) ? 1u : 0u;
    cu += (unsigned)__shfl_xor((int)cu, 16, 64);
    cu += (unsigned)__shfl_xor((int)cu, 32, 64);
    cAcc += cu;

    if (s == 0 && lab == ak) {
      unsigned pos = atomicAdd(&sCorr, 1u);
      sList[pos] = (unsigned char)(it * 16 + wave * 4 + grp);
    }
  }

  // epilogue: per-block partials (plain global stores, no atomics)
  if (lane < 8) sRd[wave][lane] = rAcc;
  if (lane < 8 && !(lane & 1)) sC4[wave][lane >> 1] = cAcc;
  __syncthreads();
  if (tid < 8)
    ws->partR[blockIdx.x][tid] = sRd[0][tid] + sRd[1][tid] + sRd[2][tid] + sRd[3][tid];
  if (tid < 4)
    ws->partC[blockIdx.x][tid] = sC4[0][tid] + sC4[1][tid] + sC4[2][tid] + sC4[3][tid];
  unsigned nc = sCorr;
  if (tid == 0) ws->partNc[blockIdx.x] = nc;
  if (tid < (int)nc) ws->corrTmp[blockIdx.x][tid] = sList[tid];
}

// ---------------- K2 (cooperative): red + sink2 + sink3 + target + gather + final
__global__ __launch_bounds__(256) void k_rest(
    const float* __restrict__ X, const int* __restrict__ label,
    const float* __restrict__ fng, const float* __restrict__ fnb,
    Ws* __restrict__ ws,
    float* __restrict__ out_target, float* __restrict__ out_protos) {
  cg::grid_group grid = cg::this_grid();

  __shared__ float fa[4 * 2048];   // gather accumulator, per-wave copies (32 KB)
  __shared__ double sRed[256];
  __shared__ float Rf8[8], su1[8], su2[8], su3[8], sBn[4];
  __shared__ unsigned ldc[4][8];

  const int tid = threadIdx.x;
  const int bid = blockIdx.x;
  const int G = GREST;
  const int wave = tid >> 6, lane = tid & 63;

  // zero spread accumulators (ordered before gather-stage use by grid syncs)
  if (bid < 8) {
    for (int i = tid; i < 2048; i += 256) ws->fAccP[bid][i] = 0.f;
    if (tid < 8) ws->nmkP[bid][tid] = 0u;
  }

  // ---- red R0 -> su1, Bn (redundant per-block) ----
  {
    int j = tid & 7;
    double acc = 0.0;
    for (int i = tid >> 3; i < NBLK; i += 32) acc += ws->partR[i][j];
    sRed[tid] = acc;
    __syncthreads();
    if (tid < 8) {
      double t = 0.0;
#pragma unroll
      for (int r2 = 0; r2 < 32; r2++) t += sRed[tid + r2 * 8];
      Rf8[tid] = (float)t;
    }
    __syncthreads();
    if (tid < 8) {
      int c = tid >> 1;
      float S = Rf8[c * 2] + Rf8[c * 2 + 1];
      float uu0 = 1.0f / fmaxf(S, 1e-30f);
      su1[tid] = uu0 / (fmaxf(uu0 * Rf8[tid], 1e-30f) * 2.0f);
    }
    __syncthreads();
    unsigned* sRu = (unsigned*)sRed;
    unsigned ua = 0;
    for (int i = tid >> 2; i < NBLK; i += 64) ua += ws->partC[i][tid & 3];
    sRu[tid] = ua;
    __syncthreads();
    if (tid < 4) {
      unsigned t = 0;
#pragma unroll
      for (int r2 = 0; r2 < 64; r2++) t += sRu[tid + r2 * 4];
      sBn[tid] = fmaxf((float)t, 1.0f);
    }
    __syncthreads();
  }

  // ---- sink iter 2 partials ----
  {
    double a0 = 0, a1 = 0, a2 = 0, a3 = 0, a4 = 0, a5 = 0, a6 = 0, a7 = 0;
    int T = G * 256;
    for (int n = bid * 256 + tid; n < N_PIX; n += T) {
      int c = label[n];
      float2 e = ws->E2[n];
      float S1 = su1[c * 2] * e.x + su1[c * 2 + 1] * e.y;
      float v1 = 1.0f / (fmaxf(S1, 1e-30f) * sBn[c]);
      double t0 = (double)(v1 * e.x), t1 = (double)(v1 * e.y);
      if (c == 0) { a0 += t0; a1 += t1; }
      else if (c == 1) { a2 += t0; a3 += t1; }
      else if (c == 2) { a4 += t0; a5 += t1; }
      else { a6 += t0; a7 += t1; }
    }
    a0 = wredd(a0); a1 = wredd(a1); a2 = wredd(a2); a3 = wredd(a3);
    a4 = wredd(a4); a5 = wredd(a5); a6 = wredd(a6); a7 = wredd(a7);
    __syncthreads();
    double* sD = sRed;
    if (lane == 0) {
      sD[wave * 8 + 0] = a0; sD[wave * 8 + 1] = a1; sD[wave * 8 + 2] = a2; sD[wave * 8 + 3] = a3;
      sD[wave * 8 + 4] = a4; sD[wave * 8 + 5] = a5; sD[wave * 8 + 6] = a6; sD[wave * 8 + 7] = a7;
    }
    __syncthreads();
    if (tid < 8)
      ws->partR2[bid][tid] = sD[tid] + sD[8 + tid] + sD[16 + tid] + sD[24 + tid];
  }

  grid.sync();   // ---- R1 complete ----

  // ---- red R1 -> su2 ----
  {
    int j = tid & 7;
    double acc = 0.0;
    for (int i = tid >> 3; i < GREST; i += 32) acc += ws->partR2[i][j];
    __syncthreads();
    sRed[tid] = acc;
    __syncthreads();
    if (tid < 8) {
      double t = 0.0;
#pragma unroll
      for (int r2 = 0; r2 < 32; r2++) t += sRed[tid + r2 * 8];
      float R1f = (float)t;
      su2[tid] = su1[tid] / (fmaxf(su1[tid] * R1f, 1e-30f) * 2.0f);
    }
    __syncthreads();
  }

  // ---- sink iter 3 partials ----
  {
    double a0 = 0, a1 = 0, a2 = 0, a3 = 0, a4 = 0, a5 = 0, a6 = 0, a7 = 0;
    int T = G * 256;
    for (int n = bid * 256 + tid; n < N_PIX; n += T) {
      int c = label[n];
      float2 e = ws->E2[n];
      float S1 = su1[c * 2] * e.x + su1[c * 2 + 1] * e.y;
      float v1 = 1.0f / (fmaxf(S1, 1e-30f) * sBn[c]);
      float S2 = su2[c * 2] * e.x + su2[c * 2 + 1] * e.y;
      float v = v1 / (fmaxf(v1 * S2, 1e-30f) * sBn[c]);
      double t0 = (double)(v * e.x), t1 = (double)(v * e.y);
      if (c == 0) { a0 += t0; a1 += t1; }
      else if (c == 1) { a2 += t0; a3 += t1; }
      else if (c == 2) { a4 += t0; a5 += t1; }
      else { a6 += t0; a7 += t1; }
    }
    a0 = wredd(a0); a1 = wredd(a1); a2 = wredd(a2); a3 = wredd(a3);
    a4 = wredd(a4); a5 = wredd(a5); a6 = wredd(a6); a7 = wredd(a7);
    __syncthreads();
    double* sD = sRed;
    if (lane == 0) {
      sD[wave * 8 + 0] = a0; sD[wave * 8 + 1] = a1; sD[wave * 8 + 2] = a2; sD[wave * 8 + 3] = a3;
      sD[wave * 8 + 4] = a4; sD[wave * 8 + 5] = a5; sD[wave * 8 + 6] = a6; sD[wave * 8 + 7] = a7;
    }
    __syncthreads();
    if (tid < 8)
      ws->partR3[bid][tid] = sD[tid] + sD[8 + tid] + sD[16 + tid] + sD[24 + tid];
  }

  grid.sync();   // ---- R2 complete ----

  // ---- red R2 -> su3 ----
  {
    int j = tid & 7;
    double acc = 0.0;
    for (int i = tid >> 3; i < GREST; i += 32) acc += ws->partR3[i][j];
    __syncthreads();
    sRed[tid] = acc;
    __syncthreads();
    if (tid < 8) {
      double t = 0.0;
#pragma unroll
      for (int r2 = 0; r2 < 32; r2++) t += sRed[tid + r2 * 8];
      float R2f = (float)t;
      su3[tid] = su2[tid] / (fmaxf(su2[tid] * R2f, 1e-30f) * 2.0f);
    }
    __syncthreads();
  }

  // ---- proto_target (all pixels) + per-chunk gather of correct pixels ----
  {
    int T = G * 256;
    for (int n = bid * 256 + tid; n < N_PIX; n += T) {
      int c = label[n];
      float2 e = ws->E2[n];
      int idx = (su3[c * 2 + 1] * e.y > su3[c * 2] * e.x) ? 1 : 0;
      out_target[n] = (float)(idx + 2 * c);
    }

    float* myAcc = &fa[wave * 2048];
    for (int i = lane; i < 2048; i += 64) myAcc[i] = 0.f;
    __syncthreads();

    const float4 g4 = *(const float4*)(fng + lane * 4);
    const float4 b4 = *(const float4*)(fnb + lane * 4);
    unsigned cl[8] = {0, 0, 0, 0, 0, 0, 0, 0};
    unsigned gw = bid * 4 + wave;
    unsigned GW = G * 4;
    for (unsigned b = gw; b < NBLK; b += GW) {
      unsigned cnt = ws->partNc[b];
      const unsigned char* lst = ws->corrTmp[b];
      for (unsigned base = 0; base < cnt; base += 4) {
        int m = (int)min(4u, cnt - base);
        int bk[4]; float4 xx[4];
#pragma unroll
        for (int g = 0; g < 4; g++) if (g < m) {
          int n = (int)(b * 128u) + (int)lst[base + g];
          int c = label[n];
          float2 e = ws->E2[n];
          int idx = (su3[c * 2 + 1] * e.y > su3[c * 2] * e.x) ? 1 : 0;
          bk[g] = c * 2 + idx;
          xx[g] = *(const float4*)(X + (size_t)n * 256 + lane * 4);
        }
        float svr[4], qvr[4];
#pragma unroll
        for (int g = 0; g < 4; g++) if (g < m) {
          float4 x = xx[g];
          float sv = x.x + x.y + x.z + x.w;
          float qv = x.x * x.x + x.y * x.y + x.z * x.z + x.w * x.w;
          svr[g] = wredf(sv); qvr[g] = wredf(qv);
        }
        float4 yy[4]; float qqr[4];
#pragma unroll
        for (int g = 0; g < 4; g++) if (g < m) {
          float mu = svr[g] * (1.0f / 256.0f);
          float var = qvr[g] * (1.0f / 256.0f) - mu * mu;
          float rstd = rsqrtf(var + LN_EPS);
          float4 x = xx[g];
          float4 y;
          y.x = (x.x - mu) * rstd * g4.x + b4.x;
          y.y = (x.y - mu) * rstd * g4.y + b4.y;
          y.z = (x.z - mu) * rstd * g4.z + b4.z;
          y.w = (x.w - mu) * rstd * g4.w + b4.w;
          yy[g] = y;
          qqr[g] = wredf(y.x * y.x + y.y * y.y + y.z * y.z + y.w * y.w);
        }
#pragma unroll
        for (int g = 0; g < 4; g++) if (g < m) {
          float invq = 1.0f / fmaxf(sqrtf(qqr[g]), 1e-12f);
          float4 y = yy[g];
          float* dst = myAcc + bk[g] * 256 + lane * 4;
          dst[0] += y.x * invq; dst[1] += y.y * invq;
          dst[2] += y.z * invq; dst[3] += y.w * invq;
          if (lane == 0) cl[bk[g]]++;
        }
      }
    }
    if (lane == 0) {
#pragma unroll
      for (int j = 0; j < 8; j++) ldc[wave][j] = cl[j];
    }
    __syncthreads();
    float* fg = &ws->fAccP[bid & 7][0];
    for (int i = tid; i < 2048; i += 256) {
      float ssum = fa[i] + fa[2048 + i] + fa[4096 + i] + fa[6144 + i];
      unsafeAtomicAdd(fg + i, ssum);
    }
    if (tid < 8) {
      unsigned cs = ldc[0][tid] + ldc[1][tid] + ldc[2][tid] + ldc[3][tid];
      if (cs) atomicAdd(&ws->nmkP[bid & 7][tid], cs);
    }
  }

  grid.sync();   // ---- fAcc / nmk complete ----

  // ---- finalize prototypes (blocks 0..7, wave 0) ----
  if (bid < 8 && wave == 0) {
    int r = bid;
    float4 f = {0.f, 0.f, 0.f, 0.f};
#pragma unroll
    for (int p = 0; p < 8; p++) {
      const float4 t = *(const float4*)(&ws->fAccP[p][r * 256 + lane * 4]);
      f.x += t.x; f.y += t.y; f.z += t.z; f.w += t.w;
    }
    unsigned nr = 0, nsib = 0;
#pragma unroll
    for (int p = 0; p < 8; p++) { nr += ws->nmkP[p][r]; nsib += ws->nmkP[p][r ^ 1]; }
    float ss = wredf(f.x * f.x + f.y * f.y + f.z * f.z + f.w * f.w);
    float invf = 1.0f / fmaxf(sqrtf(ss), 1e-12f);
    unsigned tot = nr + nsib;
    bool cond = (tot > 0u) && (nr != 0u);
    const float4 p4 = *(const float4*)(&ws->protoN[r][lane * 4]);
    float u0 = cond ? 0.999f * p4.x + 0.001f * (f.x * invf) : p4.x;
    float u1 = cond ? 0.999f * p4.y + 0.001f * (f.y * invf) : p4.y;
    float u2 = cond ? 0.999f * p4.z + 0.001f * (f.z * invf) : p4.z;
    float u3 = cond ? 0.999f * p4.w + 0.001f * (f.w * invf) : p4.w;
    float ss2 = wredf(u0 * u0 + u1 * u1 + u2 * u2 + u3 * u3);
    float invn = 1.0f / fmaxf(sqrtf(ss2), 1e-12f);
    float4 o; o.x = u0 * invn; o.y = u1 * invn; o.z = u2 * invn; o.w = u3 * invn;
    *(float4*)(out_protos + r * 256 + lane * 4) = o;
  }
}

// ---------------- launch ----------------
extern "C" void kernel_launch(void* const* d_in, const int* in_sizes, int n_in,
                              void* d_out, int out_size, void* d_ws, size_t ws_size,
                              hipStream_t stream) {
  const float* X = (const float*)d_in[0];
  const int* label = (const int*)d_in[1];
  const float* protos = (const float*)d_in[2];
  const float* fng = (const float*)d_in[3];
  const float* fnb = (const float*)d_in[4];
  const float* mng = (const float*)d_in[5];
  const float* mnb = (const float*)d_in[6];

  float* out = (float*)d_out;
  float* out_nearest = out;                        // 32*4*12544 = 1605632
  float* out_logits = out + 1605632;               // N*8 = 3211264
  float* out_target = out_logits + 3211264;        // N
  float* out_protos = out_target + N_PIX;          // 2048
  Ws* ws = (Ws*)d_ws;

  k_main<<<NBLK, 256, 0, stream>>>(X, label, protos, fng, fnb, mng, mnb, ws,
                                   out_nearest, out_logits);

  void* args[] = {(void*)&X, (void*)&label, (void*)&fng, (void*)&fnb,
                  (void*)&ws, (void*)&out_target, (void*)&out_protos};
  hipLaunchCooperativeKernel((void*)k_rest, dim3(GREST), dim3(256), args, 0, stream);
}